// Round 2
// baseline (4850.219 us; speedup 1.0000x reference)
//
#include <hip/hip_runtime.h>
#include <hip/hip_bf16.h>

// LSTM T=4096, B=16, I=64, H=256 (4H=1024 gate rows), O=1.
//
// R17 = R16 RETRY (round-1 bench was an infra failure: "container failed
// twice", no compile/validation diagnostics; kernel has no hang modes —
// barrier structure identical to verified R13/R15).
//
// R16: HYBRID PIPE-SPLIT. R13/R15 sat at the i8-MFMA issue floor: 256
// broadcast-redundant MFMAs/step/CU = 1306 cyc while VALU idled. Split K:
//   - MFMA keeps K[0,128): 8 mfma_i32_16x16x64_i8 per wave  (653 cyc/SIMD)
//   - VALU does K[128,256) via v_dot4_i32_i8: lane l owns gate-row
//     (gate=l>>4, unit=w*16+(l&15)), 32 sdot4/lane        (~256 cyc/SIMD)
//   - 4x ds_bpermute gathers the int32 dot partials into the canonical
//     all-lane layout; epilogue unchanged except 4 int adds.
// Same int8 weights + per-row scales, int32 accumulation associative =>
// bit-identical result to R13 (absmax 0.001953125 expected unchanged).
//
// Structure (verified R10/R11/R13): 16 WGs x 1024 thr (16 waves, 4/SIMD).
// Wave w, lane col=l&15 owns unit u=w*16+col; gate rows g*256+u. Per-gate-
// row symmetric int8 quant, preact = (rowmax/127^2)*acc_int + xg, int32
// exact. h int8 in LDS identity layout (b128 broadcast, 0 conflicts),
// double-buffered; magic-number RNE h-quantize; ONE barrier/step; all-lane
// redundant epilogue; xg fp16 [t][b][u*4+g] prefetched via pointer.

typedef _Float16 f16x2 __attribute__((ext_vector_type(2)));
typedef _Float16 f16x4 __attribute__((ext_vector_type(4)));
typedef int      i32x4 __attribute__((ext_vector_type(4)));

#define T_STEPS 4096
#define BATCH   16
#define IN      64
#define HID     256
#define G4      1024

__device__ __forceinline__ float fdot2(f16x2 a, f16x2 b, float c) {
#if __has_builtin(__builtin_amdgcn_fdot2)
    return __builtin_amdgcn_fdot2(a, b, c, false);
#else
    return c + (float)a.x * (float)b.x + (float)a.y * (float)b.y;
#endif
}

__device__ __forceinline__ int sdot4(int a, int b, int c) {
#if __has_builtin(__builtin_amdgcn_sdot4)
    return __builtin_amdgcn_sdot4(a, b, c, false);
#else
    c += (int)(signed char)(a & 0xff)         * (int)(signed char)(b & 0xff);
    c += (int)(signed char)((a >> 8) & 0xff)  * (int)(signed char)((b >> 8) & 0xff);
    c += (int)(signed char)((a >> 16) & 0xff) * (int)(signed char)((b >> 16) & 0xff);
    c += (int)(signed char)(a >> 24)          * (int)(signed char)(b >> 24);
    return c;
#endif
}

__device__ __forceinline__ float fast_rcp(float x) {
#if __has_builtin(__builtin_amdgcn_rcpf)
    return __builtin_amdgcn_rcpf(x);
#else
    return 1.0f / x;
#endif
}

__device__ __forceinline__ float sigf(float x) {
    return fast_rcp(1.0f + __expf(-x));
}
__device__ __forceinline__ float tanh_fast(float x) {
    return 2.0f * sigf(2.0f * x) - 1.0f;
}

// ---------------- Kernel A: x_gates precompute (transposed store) ----------
__global__ __launch_bounds__(256) void xg_precompute(
    const float* __restrict__ x, const float* __restrict__ W_ih,
    const float* __restrict__ b_ih, const float* __restrict__ b_hh,
    _Float16* __restrict__ xg)
{
    const int b   = blockIdx.x;
    const int t0  = blockIdx.y * 128;
    const int tid = threadIdx.x;

    __shared__ __align__(16) f16x2 xs2[IN / 2];

    f16x2 wih[4][32];
    float bias[4];
    const float2* W2 = (const float2*)W_ih;
    #pragma unroll
    for (int g = 0; g < 4; ++g) {
        const int r = tid + g * 256;
        #pragma unroll
        for (int m = 0; m < 32; ++m) {
            float2 v = W2[r * 32 + m];
            wih[g][m] = f16x2{(_Float16)v.x, (_Float16)v.y};
        }
        bias[g] = b_ih[r] + b_hh[r];
    }

    for (int tt = 0; tt < 128; ++tt) {
        const int t = t0 + tt;
        if (tid < 32) {
            float2 v = ((const float2*)x)[(t * BATCH + b) * 32 + tid];
            xs2[tid] = f16x2{(_Float16)v.x, (_Float16)v.y};
        }
        __syncthreads();
        float acc[4] = {bias[0], bias[1], bias[2], bias[3]};
        #pragma unroll
        for (int m = 0; m < 32; ++m) {
            f16x2 xv = xs2[m];
            #pragma unroll
            for (int g = 0; g < 4; ++g) acc[g] = fdot2(wih[g][m], xv, acc[g]);
        }
        f16x4 v4 = f16x4{(_Float16)acc[0], (_Float16)acc[1],
                         (_Float16)acc[2], (_Float16)acc[3]};
        ((f16x4*)xg)[(t * BATCH + b) * 256 + tid] = v4;
        __syncthreads();
    }
}

// ---------------- Kernel B: hybrid i8-MFMA + sdot4 persistent recurrence ---
__global__ __launch_bounds__(1024, 4) void lstm_mfma(
    const float* __restrict__ W_hh,  const float* __restrict__ W_lin,
    const float* __restrict__ b_lin, const float* __restrict__ h0,
    const float* __restrict__ c0,    const _Float16* __restrict__ xg,
    float* __restrict__ out)
{
    const int b   = blockIdx.x;
    const int tid = threadIdx.x;
    const int w   = tid >> 6;     // wave 0..15
    const int l   = tid & 63;     // lane
    const int col = l & 15;       // MFMA col for this lane
    const int g4  = l >> 4;       // k lane-group 0..3

    __shared__ __align__(16) signed char hs[2][256];  // h int8, identity layout
    __shared__ float esh[256];

    const int u = w * 16 + col;   // unit this lane covers

    // ---- one-time: per-gate-row max, then W_hh -> int8 fragments ----
    const float4* Wh4 = (const float4*)W_hh;          // row stride 64 float4
    float qs[4], ksc[4];
    {
        float rm[4];
        #pragma unroll
        for (int g = 0; g < 4; ++g) {
            const int row = g * 256 + u;
            float m = 0.0f;
            #pragma unroll
            for (int c = 0; c < 4; ++c) {
                #pragma unroll
                for (int d = 0; d < 4; ++d) {
                    float4 v = Wh4[row * 64 + 16 * c + 4 * g4 + d];
                    m = fmaxf(m, fmaxf(fmaxf(fabsf(v.x), fabsf(v.y)),
                                       fmaxf(fabsf(v.z), fabsf(v.w))));
                }
            }
            rm[g] = m;
        }
        #pragma unroll
        for (int g = 0; g < 4; ++g) {                  // max across g4 groups
            rm[g] = fmaxf(rm[g], __shfl_xor(rm[g], 16, 64));
            rm[g] = fmaxf(rm[g], __shfl_xor(rm[g], 32, 64));
            rm[g] = fmaxf(rm[g], 1e-20f);
            qs[g]  = 127.0f / rm[g];
            ksc[g] = rm[g] * (1.0f / 16129.0f);        // rm/127^2
        }
    }

    // MFMA B-fragments: K[0,128) only (chunks 0,1)
    i32x4 wf[4][2];
    #pragma unroll
    for (int g = 0; g < 4; ++g) {
        const int row = g * 256 + u;
        #pragma unroll
        for (int c = 0; c < 2; ++c) {
            union { int i[4]; i32x4 v; } uu;
            #pragma unroll
            for (int d = 0; d < 4; ++d) {
                float4 v = Wh4[row * 64 + 16 * c + 4 * g4 + d];
                int b0 = (int)rintf(v.x * qs[g]) & 255;
                int b1 = (int)rintf(v.y * qs[g]) & 255;
                int b2 = (int)rintf(v.z * qs[g]) & 255;
                int b3 = (int)rintf(v.w * qs[g]) & 255;
                uu.i[d] = b0 | (b1 << 8) | (b2 << 16) | (b3 << 24);
            }
            wf[g][c] = uu.v;
        }
    }

    // sdot4 weights: this lane owns gate-row (g4*256 + u), K[128,256)
    const float qsd = (g4 & 2) ? ((g4 & 1) ? qs[3] : qs[2])
                               : ((g4 & 1) ? qs[1] : qs[0]);
    int wd[32];
    {
        const int rg = g4 * 256 + u;
        #pragma unroll
        for (int q = 0; q < 32; ++q) {
            float4 v = Wh4[rg * 64 + 32 + q];
            int b0 = (int)rintf(v.x * qsd) & 255;
            int b1 = (int)rintf(v.y * qsd) & 255;
            int b2 = (int)rintf(v.z * qsd) & 255;
            int b3 = (int)rintf(v.w * qsd) & 255;
            wd[q] = b0 | (b1 << 8) | (b2 << 16) | (b3 << 24);
        }
    }

    // bpermute byte-indices: gate g's partial for my col lives in lane g*16+col
    const int bp0 = (col)      << 2;
    const int bp1 = (16 + col) << 2;
    const int bp2 = (32 + col) << 2;
    const int bp3 = (48 + col) << 2;

    // ---- state (lane l<16 owns unit u's write) ----
    const float MAGIC = 12582912.0f;                   // 1.5 * 2^23
    float cst  = c0[b * HID + u];
    float hval = h0[b * HID + u];
    if (l < 16) {
        union { float f; int i; } m0;
        m0.f = __builtin_fmaf(hval, 127.0f, MAGIC);    // RNE int in low bits
        hs[0][u] = (signed char)(m0.i & 0xff);
    }

    union XU { uint2 i; f16x4 h; };
    const uint2* xp = (const uint2*)xg + b * 256 + u;  // stride BATCH*256/step
    XU xc; xc.i = *xp;
    xp += BATCH * 256;

    for (int t = 0; t < T_STEPS; ++t) {
        __syncthreads();   // h(t) in hs[t&1] visible

        const uint4* hsv = (const uint4*)(&hs[t & 1][0]);

        // A fragments for K[0,128): chunks 0,1 -> b128 broadcast
        union AU { uint4 q; i32x4 v; } a0, a1;
        a0.q = hsv[g4];
        a1.q = hsv[4 + g4];

        // prefetch next step's x-gates (pointer-incremented)
        XU xn;
        if (t + 1 < T_STEPS) { xn.i = *xp; xp += BATCH * 256; }
        else                 { xn = xc; }

        i32x4 acc0 = {0, 0, 0, 0};
        i32x4 acc1 = {0, 0, 0, 0};
        i32x4 acc2 = {0, 0, 0, 0};
        i32x4 acc3 = {0, 0, 0, 0};

        acc0 = __builtin_amdgcn_mfma_i32_16x16x64_i8(a0.v, wf[0][0], acc0, 0, 0, 0);
        acc1 = __builtin_amdgcn_mfma_i32_16x16x64_i8(a0.v, wf[1][0], acc1, 0, 0, 0);
        acc2 = __builtin_amdgcn_mfma_i32_16x16x64_i8(a0.v, wf[2][0], acc2, 0, 0, 0);
        acc3 = __builtin_amdgcn_mfma_i32_16x16x64_i8(a0.v, wf[3][0], acc3, 0, 0, 0);
        acc0 = __builtin_amdgcn_mfma_i32_16x16x64_i8(a1.v, wf[0][1], acc0, 0, 0, 0);
        acc1 = __builtin_amdgcn_mfma_i32_16x16x64_i8(a1.v, wf[1][1], acc1, 0, 0, 0);
        acc2 = __builtin_amdgcn_mfma_i32_16x16x64_i8(a1.v, wf[2][1], acc2, 0, 0, 0);
        acc3 = __builtin_amdgcn_mfma_i32_16x16x64_i8(a1.v, wf[3][1], acc3, 0, 0, 0);

        // VALU half: K[128,256) for my gate-row via sdot4 (4 indep chains)
        int da0 = 0, da1 = 0, da2 = 0, da3 = 0;
        #pragma unroll
        for (int qb = 0; qb < 2; ++qb) {
            uint4 q0 = hsv[8 + qb * 4 + 0];
            uint4 q1 = hsv[8 + qb * 4 + 1];
            uint4 q2 = hsv[8 + qb * 4 + 2];
            uint4 q3 = hsv[8 + qb * 4 + 3];
            da0 = sdot4((int)q0.x, wd[qb * 16 + 0],  da0);
            da1 = sdot4((int)q0.y, wd[qb * 16 + 1],  da1);
            da2 = sdot4((int)q0.z, wd[qb * 16 + 2],  da2);
            da3 = sdot4((int)q0.w, wd[qb * 16 + 3],  da3);
            da0 = sdot4((int)q1.x, wd[qb * 16 + 4],  da0);
            da1 = sdot4((int)q1.y, wd[qb * 16 + 5],  da1);
            da2 = sdot4((int)q1.z, wd[qb * 16 + 6],  da2);
            da3 = sdot4((int)q1.w, wd[qb * 16 + 7],  da3);
            da0 = sdot4((int)q2.x, wd[qb * 16 + 8],  da0);
            da1 = sdot4((int)q2.y, wd[qb * 16 + 9],  da1);
            da2 = sdot4((int)q2.z, wd[qb * 16 + 10], da2);
            da3 = sdot4((int)q2.w, wd[qb * 16 + 11], da3);
            da0 = sdot4((int)q3.x, wd[qb * 16 + 12], da0);
            da1 = sdot4((int)q3.y, wd[qb * 16 + 13], da1);
            da2 = sdot4((int)q3.z, wd[qb * 16 + 14], da2);
            da3 = sdot4((int)q3.w, wd[qb * 16 + 15], da3);
        }
        const int dacc = (da0 + da1) + (da2 + da3);

        // gather dot partials into canonical per-lane gate order
        const int dp0 = __builtin_amdgcn_ds_bpermute(bp0, dacc);
        const int dp1 = __builtin_amdgcn_ds_bpermute(bp1, dacc);
        const int dp2 = __builtin_amdgcn_ds_bpermute(bp2, dacc);
        const int dp3 = __builtin_amdgcn_ds_bpermute(bp3, dacc);

        // D rows identical -> acc reg0 of ANY lane = int preact(col) partial.
        // All-lane redundant epilogue (issue hides under MFMA shadow).
        float gi = sigf((float)(acc0[0] + dp0) * ksc[0] + (float)xc.h[0]);
        float gf = sigf((float)(acc1[0] + dp1) * ksc[1] + (float)xc.h[1]);
        float gg = tanh_fast((float)(acc2[0] + dp2) * ksc[2] + (float)xc.h[2]);
        float go = sigf((float)(acc3[0] + dp3) * ksc[3] + (float)xc.h[3]);
        cst  = gf * cst + gi * gg;
        hval = go * tanh_fast(cst);
        if (l < 16) {
            union { float f; int i; } mg;
            mg.f = __builtin_fmaf(hval, 127.0f, MAGIC);   // RNE, low byte = i8
            hs[(t + 1) & 1][u] = (signed char)(mg.i & 0xff);
        }
        xc = xn;
    }

    // ---- epilogue: y[b] = sigmoid(h . W_lin + b_lin) ----
    if (l < 16) esh[u] = hval * W_lin[u];
    __syncthreads();
    if (tid == 0) {
        float z = b_lin[0];
        for (int n = 0; n < 256; ++n) z += esh[n];
        out[b] = sigf(z);
    }
}

// ---------------- Fallback (ws too small): R6 dot2 kernel, x streamed ------
#define NTHR 768
#define KC   11
#define REGC 8
#define LDSC 3
#define HPAD 264
#define WT_OFF   0
#define HB_OFF   147456
#define PS_OFF   148512
#define ESH_OFF  156704
#define SMEM_BYTES 157728
typedef _Float16 f16x8 __attribute__((ext_vector_type(8)));

__global__ __launch_bounds__(NTHR, 3) void lstm_fb(
    const float* __restrict__ x,     const float* __restrict__ W_ih,
    const float* __restrict__ W_hh,  const float* __restrict__ b_ih,
    const float* __restrict__ b_hh,  const float* __restrict__ W_lin,
    const float* __restrict__ b_lin, const float* __restrict__ h0,
    const float* __restrict__ c0,    float* __restrict__ out)
{
    const int b   = blockIdx.x;
    const int tid = threadIdx.x;
    const int j   = tid & 255;
    const int s   = tid >> 8;

    extern __shared__ __align__(16) char smem[];
    f16x8*    wt8  = (f16x8*)(smem + WT_OFF);
    _Float16* hbuf = (_Float16*)(smem + HB_OFF);
    float4*   psum = (float4*)(smem + PS_OFF);
    float*    esh  = (float*)(smem + ESH_OFF);

    f16x2 wr[128];
    const float4* Wh4 = (const float4*)W_hh;
    #pragma unroll
    for (int g = 0; g < 4; ++g) {
        const int r = j + 256 * g;
        #pragma unroll
        for (int c = 0; c < REGC; ++c) {
            const int f4i = r * 64 + (88 * s + 8 * c) / 4;
            float4 a = Wh4[f4i];
            float4 d = Wh4[f4i + 1];
            wr[g * 32 + c * 4 + 0] = f16x2{(_Float16)a.x, (_Float16)a.y};
            wr[g * 32 + c * 4 + 1] = f16x2{(_Float16)a.z, (_Float16)a.w};
            wr[g * 32 + c * 4 + 2] = f16x2{(_Float16)d.x, (_Float16)d.y};
            wr[g * 32 + c * 4 + 3] = f16x2{(_Float16)d.z, (_Float16)d.w};
        }
        #pragma unroll
        for (int c = 0; c < LDSC; ++c) {
            const int k0 = 88 * s + 8 * (REGC + c);
            union { f16x8 v; f16x2 p[4]; } u;
            if (k0 < 256) {
                float4 a = Wh4[r * 64 + k0 / 4];
                float4 d = Wh4[r * 64 + k0 / 4 + 1];
                u.p[0] = f16x2{(_Float16)a.x, (_Float16)a.y};
                u.p[1] = f16x2{(_Float16)a.z, (_Float16)a.w};
                u.p[2] = f16x2{(_Float16)d.x, (_Float16)d.y};
                u.p[3] = f16x2{(_Float16)d.z, (_Float16)d.w};
            } else {
                u.p[0] = f16x2{0, 0}; u.p[1] = f16x2{0, 0};
                u.p[2] = f16x2{0, 0}; u.p[3] = f16x2{0, 0};
            }
            wt8[(g * LDSC + c) * NTHR + tid] = u.v;
        }
    }

    float bias[4] = {0.f, 0.f, 0.f, 0.f};
    if (s == 0) {
        #pragma unroll
        for (int g = 0; g < 4; ++g)
            bias[g] = b_ih[j + g * 256] + b_hh[j + g * 256];
    }

    float cst = 0.f, hval = 0.f;
    if (s == 0) {
        cst  = c0[b * HID + j];
        hval = h0[b * HID + j];
        hbuf[j] = (_Float16)hval;
    }
    if (tid < 8) {
        hbuf[256 + tid]        = (_Float16)0.f;
        hbuf[HPAD + 256 + tid] = (_Float16)0.f;
    }

    for (int t = 0; t < T_STEPS; ++t) {
        __syncthreads();
        const f16x8* hb = (const f16x8*)(hbuf + (t & 1) * HPAD);

        float acc[4] = {0.f, 0.f, 0.f, 0.f};
        if (s != 0) {
            const float4* Wi4 = (const float4*)W_ih;
            const float4* xv4 = (const float4*)(x + ((size_t)t * BATCH + b) * IN)
                                + (s - 1) * 8;
            #pragma unroll
            for (int q = 0; q < 8; ++q) {
                float4 xv = xv4[q];
                #pragma unroll
                for (int g = 0; g < 4; ++g) {
                    float4 wv = Wi4[(j + 256 * g) * 16 + (s - 1) * 8 + q];
                    acc[g] += wv.x * xv.x + wv.y * xv.y + wv.z * xv.z + wv.w * xv.w;
                }
            }
        }
        #pragma unroll
        for (int c = 0; c < REGC; ++c) {
            union { f16x8 v; f16x2 p[4]; } hu;
            hu.v = hb[s * KC + c];
            #pragma unroll
            for (int uu = 0; uu < 4; ++uu) {
                #pragma unroll
                for (int g = 0; g < 4; ++g)
                    acc[g] = fdot2(wr[g * 32 + c * 4 + uu], hu.p[uu], acc[g]);
            }
        }
        #pragma unroll
        for (int c = 0; c < LDSC; ++c) {
            union { f16x8 v; f16x2 p[4]; } hu;
            hu.v = hb[s * KC + REGC + c];
            #pragma unroll
            for (int g = 0; g < 4; ++g) {
                union { f16x8 v; f16x2 p[4]; } wu;
                wu.v = wt8[(g * LDSC + c) * NTHR + tid];
                #pragma unroll
                for (int uu = 0; uu < 4; ++uu)
                    acc[g] = fdot2(wu.p[uu], hu.p[uu], acc[g]);
            }
        }
        if (s != 0)
            psum[(s - 1) * 256 + j] = float4{acc[0], acc[1], acc[2], acc[3]};
        __syncthreads();
        if (s == 0) {
            float4 p1 = psum[j];
            float4 p2 = psum[256 + j];
            float gi = sigf(acc[0] + p1.x + p2.x + bias[0]);
            float gf = sigf(acc[1] + p1.y + p2.y + bias[1]);
            float gg = tanh_fast(acc[2] + p1.z + p2.z + bias[2]);
            float go = sigf(acc[3] + p1.w + p2.w + bias[3]);
            cst  = gf * cst + gi * gg;
            hval = go * tanh_fast(cst);
            hbuf[((t + 1) & 1) * HPAD + j] = (_Float16)hval;
        }
    }

    if (s == 0) esh[j] = hval * W_lin[j];
    __syncthreads();
    if (tid == 0) {
        float z = b_lin[0];
        for (int n = 0; n < 256; ++n) z += esh[n];
        out[b] = sigf(z);
    }
}

extern "C" void kernel_launch(void* const* d_in, const int* in_sizes, int n_in,
                              void* d_out, int out_size, void* d_ws, size_t ws_size,
                              hipStream_t stream) {
    const float* x     = (const float*)d_in[0];
    const float* W_ih  = (const float*)d_in[1];
    const float* W_hh  = (const float*)d_in[2];
    const float* b_ih  = (const float*)d_in[3];
    const float* b_hh  = (const float*)d_in[4];
    const float* W_lin = (const float*)d_in[5];
    const float* b_lin = (const float*)d_in[6];
    const float* h0    = (const float*)d_in[7];
    const float* c0    = (const float*)d_in[8];
    float* out = (float*)d_out;

    const size_t need = (size_t)T_STEPS * BATCH * G4 * sizeof(_Float16); // 128 MB
    if (ws_size >= need) {
        _Float16* xg = (_Float16*)d_ws;
        xg_precompute<<<dim3(BATCH, 32), 256, 0, stream>>>(x, W_ih, b_ih, b_hh, xg);
        lstm_mfma<<<dim3(BATCH), 1024, 0, stream>>>(
            W_hh, W_lin, b_lin, h0, c0, xg, out);
    } else {
        (void)hipFuncSetAttribute((const void*)lstm_fb,
                                  hipFuncAttributeMaxDynamicSharedMemorySize,
                                  SMEM_BYTES);
        lstm_fb<<<dim3(BATCH), NTHR, SMEM_BYTES, stream>>>(
            x, W_ih, W_hh, b_ih, b_hh, W_lin, b_lin, h0, c0, out);
    }
}

// Round 3
// 4813.493 us; speedup vs baseline: 1.0076x; 1.0076x over previous
//
#include <hip/hip_runtime.h>
#include <hip/hip_bf16.h>

// LSTM T=4096, B=16, I=64, H=256 (4H=1024 gate rows), O=1.
//
// R18: HYBRID v3 (DS-budget-disciplined pipe split).
// R16 post-mortem: 8 uniform-address ds_read_b128 + 4 bpermute per wave
// pushed DS to 224 ops/CU-step ~= 2731 cyc (measured step time exactly) —
// LDS return BW charges full price for broadcast reads. Fix: VALU half's
// h operand comes from the EXISTING a3 ds_read via 16 v_readlane -> SGPRs
// (zero extra DS); gather via 1 ds_swizzle(xor16) + 2 shfl_xor(32) + 8
// cndmask instead of 4 bpermutes.
//   - MFMA: K[0,192), 12 mfma_i32_16x16x64_i8 per wave   (~979 cyc/SIMD)
//   - VALU: K[192,256): lane(g4,col) owns gate-row g4*256+u, 16 sdot4
//     with SGPR h                                          (~810 cyc/SIMD)
//   - DS: 4x b128 (same as R13) + ~3 small ops             (~960 cyc/CU)
// Integer regrouping is exact => bit-identical to R13/R16 (absmax
// 0.001953125 expected unchanged).
//
// Structure (verified R10/R11/R13): 16 WGs x 1024 thr (16 waves, 4/SIMD).
// Wave w, lane col=l&15 owns unit u=w*16+col; gate rows g*256+u. Per-gate-
// row symmetric int8 quant, preact = (rowmax/127^2)*acc_int + xg, int32
// exact. h int8 in LDS identity layout (b128 broadcast, 0 conflicts),
// double-buffered; magic-number RNE h-quantize; ONE barrier/step; all-lane
// redundant epilogue; xg fp16 [t][b][u*4+g] prefetched via pointer.

typedef _Float16 f16x2 __attribute__((ext_vector_type(2)));
typedef _Float16 f16x4 __attribute__((ext_vector_type(4)));
typedef int      i32x4 __attribute__((ext_vector_type(4)));

#define T_STEPS 4096
#define BATCH   16
#define IN      64
#define HID     256
#define G4      1024

__device__ __forceinline__ float fdot2(f16x2 a, f16x2 b, float c) {
#if __has_builtin(__builtin_amdgcn_fdot2)
    return __builtin_amdgcn_fdot2(a, b, c, false);
#else
    return c + (float)a.x * (float)b.x + (float)a.y * (float)b.y;
#endif
}

__device__ __forceinline__ int sdot4(int a, int b, int c) {
#if __has_builtin(__builtin_amdgcn_sdot4)
    return __builtin_amdgcn_sdot4(a, b, c, false);
#else
    c += (int)(signed char)(a & 0xff)         * (int)(signed char)(b & 0xff);
    c += (int)(signed char)((a >> 8) & 0xff)  * (int)(signed char)((b >> 8) & 0xff);
    c += (int)(signed char)((a >> 16) & 0xff) * (int)(signed char)((b >> 16) & 0xff);
    c += (int)(signed char)(a >> 24)          * (int)(signed char)(b >> 24);
    return c;
#endif
}

__device__ __forceinline__ int xor16_lane(int x) {
#if __has_builtin(__builtin_amdgcn_ds_swizzle)
    return __builtin_amdgcn_ds_swizzle(x, 0x401F);   // BitMode: xor lane^16
#else
    return __shfl_xor(x, 16, 64);
#endif
}

__device__ __forceinline__ float fast_rcp(float x) {
#if __has_builtin(__builtin_amdgcn_rcpf)
    return __builtin_amdgcn_rcpf(x);
#else
    return 1.0f / x;
#endif
}

__device__ __forceinline__ float sigf(float x) {
    return fast_rcp(1.0f + __expf(-x));
}
__device__ __forceinline__ float tanh_fast(float x) {
    return 2.0f * sigf(2.0f * x) - 1.0f;
}

// ---------------- Kernel A: x_gates precompute (transposed store) ----------
__global__ __launch_bounds__(256) void xg_precompute(
    const float* __restrict__ x, const float* __restrict__ W_ih,
    const float* __restrict__ b_ih, const float* __restrict__ b_hh,
    _Float16* __restrict__ xg)
{
    const int b   = blockIdx.x;
    const int t0  = blockIdx.y * 128;
    const int tid = threadIdx.x;

    __shared__ __align__(16) f16x2 xs2[IN / 2];

    f16x2 wih[4][32];
    float bias[4];
    const float2* W2 = (const float2*)W_ih;
    #pragma unroll
    for (int g = 0; g < 4; ++g) {
        const int r = tid + g * 256;
        #pragma unroll
        for (int m = 0; m < 32; ++m) {
            float2 v = W2[r * 32 + m];
            wih[g][m] = f16x2{(_Float16)v.x, (_Float16)v.y};
        }
        bias[g] = b_ih[r] + b_hh[r];
    }

    for (int tt = 0; tt < 128; ++tt) {
        const int t = t0 + tt;
        if (tid < 32) {
            float2 v = ((const float2*)x)[(t * BATCH + b) * 32 + tid];
            xs2[tid] = f16x2{(_Float16)v.x, (_Float16)v.y};
        }
        __syncthreads();
        float acc[4] = {bias[0], bias[1], bias[2], bias[3]};
        #pragma unroll
        for (int m = 0; m < 32; ++m) {
            f16x2 xv = xs2[m];
            #pragma unroll
            for (int g = 0; g < 4; ++g) acc[g] = fdot2(wih[g][m], xv, acc[g]);
        }
        f16x4 v4 = f16x4{(_Float16)acc[0], (_Float16)acc[1],
                         (_Float16)acc[2], (_Float16)acc[3]};
        ((f16x4*)xg)[(t * BATCH + b) * 256 + tid] = v4;
        __syncthreads();
    }
}

// ---------------- Kernel B: hybrid i8-MFMA + SGPR-sdot4 recurrence --------
__global__ __launch_bounds__(1024, 4) void lstm_mfma(
    const float* __restrict__ W_hh,  const float* __restrict__ W_lin,
    const float* __restrict__ b_lin, const float* __restrict__ h0,
    const float* __restrict__ c0,    const _Float16* __restrict__ xg,
    float* __restrict__ out)
{
    const int b   = blockIdx.x;
    const int tid = threadIdx.x;
    const int w   = tid >> 6;     // wave 0..15
    const int l   = tid & 63;     // lane
    const int col = l & 15;       // MFMA col for this lane
    const int g4  = l >> 4;       // k lane-group 0..3

    __shared__ __align__(16) signed char hs[2][256];  // h int8, identity layout
    __shared__ float esh[256];

    const int u = w * 16 + col;   // unit this lane covers

    // ---- one-time: per-gate-row max, then W_hh -> int8 fragments ----
    const float4* Wh4 = (const float4*)W_hh;          // row stride 64 float4
    float qs[4], ksc[4];
    {
        float rm[4];
        #pragma unroll
        for (int g = 0; g < 4; ++g) {
            const int row = g * 256 + u;
            float m = 0.0f;
            #pragma unroll
            for (int c = 0; c < 4; ++c) {
                #pragma unroll
                for (int d = 0; d < 4; ++d) {
                    float4 v = Wh4[row * 64 + 16 * c + 4 * g4 + d];
                    m = fmaxf(m, fmaxf(fmaxf(fabsf(v.x), fabsf(v.y)),
                                       fmaxf(fabsf(v.z), fabsf(v.w))));
                }
            }
            rm[g] = m;
        }
        #pragma unroll
        for (int g = 0; g < 4; ++g) {                  // max across g4 groups
            rm[g] = fmaxf(rm[g], __shfl_xor(rm[g], 16, 64));
            rm[g] = fmaxf(rm[g], __shfl_xor(rm[g], 32, 64));
            rm[g] = fmaxf(rm[g], 1e-20f);
            qs[g]  = 127.0f / rm[g];
            ksc[g] = rm[g] * (1.0f / 16129.0f);        // rm/127^2
        }
    }

    // MFMA B-fragments: K[0,192) only (chunks 0..2)
    i32x4 wf[4][3];
    #pragma unroll
    for (int g = 0; g < 4; ++g) {
        const int row = g * 256 + u;
        #pragma unroll
        for (int c = 0; c < 3; ++c) {
            union { int i[4]; i32x4 v; } uu;
            #pragma unroll
            for (int d = 0; d < 4; ++d) {
                float4 v = Wh4[row * 64 + 16 * c + 4 * g4 + d];
                int b0 = (int)rintf(v.x * qs[g]) & 255;
                int b1 = (int)rintf(v.y * qs[g]) & 255;
                int b2 = (int)rintf(v.z * qs[g]) & 255;
                int b3 = (int)rintf(v.w * qs[g]) & 255;
                uu.i[d] = b0 | (b1 << 8) | (b2 << 16) | (b3 << 24);
            }
            wf[g][c] = uu.v;
        }
    }

    // sdot4 weights: this lane owns gate-row (g4*256 + u), K[192,256)
    const float qsd = (g4 & 2) ? ((g4 & 1) ? qs[3] : qs[2])
                               : ((g4 & 1) ? qs[1] : qs[0]);
    int wd[16];
    {
        const int rg = g4 * 256 + u;
        #pragma unroll
        for (int q = 0; q < 16; ++q) {
            float4 v = Wh4[rg * 64 + 48 + q];
            int b0 = (int)rintf(v.x * qsd) & 255;
            int b1 = (int)rintf(v.y * qsd) & 255;
            int b2 = (int)rintf(v.z * qsd) & 255;
            int b3 = (int)rintf(v.w * qsd) & 255;
            wd[q] = b0 | (b1 << 8) | (b2 << 16) | (b3 << 24);
        }
    }

    // ---- state (lane l<16 owns unit u's write) ----
    const float MAGIC = 12582912.0f;                   // 1.5 * 2^23
    float cst  = c0[b * HID + u];
    float hval = h0[b * HID + u];
    if (l < 16) {
        union { float f; int i; } m0;
        m0.f = __builtin_fmaf(hval, 127.0f, MAGIC);    // RNE int in low bits
        hs[0][u] = (signed char)(m0.i & 0xff);
    }

    union XU { uint2 i; f16x4 h; };
    const uint2* xp = (const uint2*)xg + b * 256 + u;  // stride BATCH*256/step
    XU xc; xc.i = *xp;
    xp += BATCH * 256;

    for (int t = 0; t < T_STEPS; ++t) {
        __syncthreads();   // h(t) in hs[t&1] visible

        const uint4* hsv = (const uint4*)(&hs[t & 1][0]);

        // A fragments for K[0,192): chunks 0..2 -> b128 broadcast.
        // a3 (chunk 3) is read ONLY to source the readlanes (same DS budget
        // as R13's 4 reads/wave).
        union AU { uint4 q; int i[4]; i32x4 v; } a0, a1, a2, a3;
        a0.q = hsv[g4];
        a1.q = hsv[4 + g4];
        a2.q = hsv[8 + g4];
        a3.q = hsv[12 + g4];

        // prefetch next step's x-gates (pointer-incremented)
        XU xn;
        if (t + 1 < T_STEPS) { xn.i = *xp; xp += BATCH * 256; }
        else                 { xn = xc; }

        // h[192,256) -> wave-uniform SGPRs (16 readlanes, zero DS traffic):
        // lane-group q holds ints 48+4q..51+4q in a3 regs 0..3.
        int hu[16];
        #pragma unroll
        for (int j = 0; j < 16; ++j)
            hu[j] = __builtin_amdgcn_readlane(a3.i[j & 3], 16 * (j >> 2));

        i32x4 acc0 = {0, 0, 0, 0};
        i32x4 acc1 = {0, 0, 0, 0};
        i32x4 acc2 = {0, 0, 0, 0};
        i32x4 acc3 = {0, 0, 0, 0};

        acc0 = __builtin_amdgcn_mfma_i32_16x16x64_i8(a0.v, wf[0][0], acc0, 0, 0, 0);
        acc1 = __builtin_amdgcn_mfma_i32_16x16x64_i8(a0.v, wf[1][0], acc1, 0, 0, 0);
        acc2 = __builtin_amdgcn_mfma_i32_16x16x64_i8(a0.v, wf[2][0], acc2, 0, 0, 0);
        acc3 = __builtin_amdgcn_mfma_i32_16x16x64_i8(a0.v, wf[3][0], acc3, 0, 0, 0);
        acc0 = __builtin_amdgcn_mfma_i32_16x16x64_i8(a1.v, wf[0][1], acc0, 0, 0, 0);
        acc1 = __builtin_amdgcn_mfma_i32_16x16x64_i8(a1.v, wf[1][1], acc1, 0, 0, 0);
        acc2 = __builtin_amdgcn_mfma_i32_16x16x64_i8(a1.v, wf[2][1], acc2, 0, 0, 0);
        acc3 = __builtin_amdgcn_mfma_i32_16x16x64_i8(a1.v, wf[3][1], acc3, 0, 0, 0);
        acc0 = __builtin_amdgcn_mfma_i32_16x16x64_i8(a2.v, wf[0][2], acc0, 0, 0, 0);
        acc1 = __builtin_amdgcn_mfma_i32_16x16x64_i8(a2.v, wf[1][2], acc1, 0, 0, 0);
        acc2 = __builtin_amdgcn_mfma_i32_16x16x64_i8(a2.v, wf[2][2], acc2, 0, 0, 0);
        acc3 = __builtin_amdgcn_mfma_i32_16x16x64_i8(a2.v, wf[3][2], acc3, 0, 0, 0);

        // VALU half: K[192,256) for my gate-row (gate g4, unit col):
        // 16 sdot4 with SGPR h operand, 4 independent chains.
        int d0 = 0, d1 = 0, d2 = 0, d3 = 0;
        #pragma unroll
        for (int j = 0; j < 4; ++j) {
            d0 = sdot4(hu[4 * j + 0], wd[4 * j + 0], d0);
            d1 = sdot4(hu[4 * j + 1], wd[4 * j + 1], d1);
            d2 = sdot4(hu[4 * j + 2], wd[4 * j + 2], d2);
            d3 = sdot4(hu[4 * j + 3], wd[4 * j + 3], d3);
        }
        const int dacc = (d0 + d1) + (d2 + d3);

        // gather: lane(g4,col) needs gate-g partial = dacc of lane 16g+col.
        // n16 = g4^1's, n32 = g4^2's, n48 = g4^3's value; then a static
        // xor-network of cndmasks maps them to gate order (verified map).
        const int n16 = xor16_lane(dacc);
        const int n32 = __shfl_xor(dacc, 32, 64);
        const int n48 = __shfl_xor(n16, 32, 64);
        const bool s0 = (g4 & 1) != 0;
        const bool s1 = (g4 & 2) != 0;
        const int pa0 = s0 ? n16 : dacc, pa1 = s0 ? dacc : n16;
        const int pc0 = s0 ? n48 : n32,  pc1 = s0 ? n32 : n48;
        const int dp0 = s1 ? pc0 : pa0;
        const int dp1 = s1 ? pc1 : pa1;
        const int dp2 = s1 ? pa0 : pc0;
        const int dp3 = s1 ? pa1 : pc1;

        // D rows identical -> acc reg0 of ANY lane = int preact(col) partial.
        // All-lane redundant epilogue (issue hides under MFMA shadow).
        float gi = sigf((float)(acc0[0] + dp0) * ksc[0] + (float)xc.h[0]);
        float gf = sigf((float)(acc1[0] + dp1) * ksc[1] + (float)xc.h[1]);
        float gg = tanh_fast((float)(acc2[0] + dp2) * ksc[2] + (float)xc.h[2]);
        float go = sigf((float)(acc3[0] + dp3) * ksc[3] + (float)xc.h[3]);
        cst  = gf * cst + gi * gg;
        hval = go * tanh_fast(cst);
        if (l < 16) {
            union { float f; int i; } mg;
            mg.f = __builtin_fmaf(hval, 127.0f, MAGIC);   // RNE, low byte = i8
            hs[(t + 1) & 1][u] = (signed char)(mg.i & 0xff);
        }
        xc = xn;
    }

    // ---- epilogue: y[b] = sigmoid(h . W_lin + b_lin) ----
    if (l < 16) esh[u] = hval * W_lin[u];
    __syncthreads();
    if (tid == 0) {
        float z = b_lin[0];
        for (int n = 0; n < 256; ++n) z += esh[n];
        out[b] = sigf(z);
    }
}

// ---------------- Fallback (ws too small): R6 dot2 kernel, x streamed ------
#define NTHR 768
#define KC   11
#define REGC 8
#define LDSC 3
#define HPAD 264
#define WT_OFF   0
#define HB_OFF   147456
#define PS_OFF   148512
#define ESH_OFF  156704
#define SMEM_BYTES 157728
typedef _Float16 f16x8 __attribute__((ext_vector_type(8)));

__global__ __launch_bounds__(NTHR, 3) void lstm_fb(
    const float* __restrict__ x,     const float* __restrict__ W_ih,
    const float* __restrict__ W_hh,  const float* __restrict__ b_ih,
    const float* __restrict__ b_hh,  const float* __restrict__ W_lin,
    const float* __restrict__ b_lin, const float* __restrict__ h0,
    const float* __restrict__ c0,    float* __restrict__ out)
{
    const int b   = blockIdx.x;
    const int tid = threadIdx.x;
    const int j   = tid & 255;
    const int s   = tid >> 8;

    extern __shared__ __align__(16) char smem[];
    f16x8*    wt8  = (f16x8*)(smem + WT_OFF);
    _Float16* hbuf = (_Float16*)(smem + HB_OFF);
    float4*   psum = (float4*)(smem + PS_OFF);
    float*    esh  = (float*)(smem + ESH_OFF);

    f16x2 wr[128];
    const float4* Wh4 = (const float4*)W_hh;
    #pragma unroll
    for (int g = 0; g < 4; ++g) {
        const int r = j + 256 * g;
        #pragma unroll
        for (int c = 0; c < REGC; ++c) {
            const int f4i = r * 64 + (88 * s + 8 * c) / 4;
            float4 a = Wh4[f4i];
            float4 d = Wh4[f4i + 1];
            wr[g * 32 + c * 4 + 0] = f16x2{(_Float16)a.x, (_Float16)a.y};
            wr[g * 32 + c * 4 + 1] = f16x2{(_Float16)a.z, (_Float16)a.w};
            wr[g * 32 + c * 4 + 2] = f16x2{(_Float16)d.x, (_Float16)d.y};
            wr[g * 32 + c * 4 + 3] = f16x2{(_Float16)d.z, (_Float16)d.w};
        }
        #pragma unroll
        for (int c = 0; c < LDSC; ++c) {
            const int k0 = 88 * s + 8 * (REGC + c);
            union { f16x8 v; f16x2 p[4]; } u;
            if (k0 < 256) {
                float4 a = Wh4[r * 64 + k0 / 4];
                float4 d = Wh4[r * 64 + k0 / 4 + 1];
                u.p[0] = f16x2{(_Float16)a.x, (_Float16)a.y};
                u.p[1] = f16x2{(_Float16)a.z, (_Float16)a.w};
                u.p[2] = f16x2{(_Float16)d.x, (_Float16)d.y};
                u.p[3] = f16x2{(_Float16)d.z, (_Float16)d.w};
            } else {
                u.p[0] = f16x2{0, 0}; u.p[1] = f16x2{0, 0};
                u.p[2] = f16x2{0, 0}; u.p[3] = f16x2{0, 0};
            }
            wt8[(g * LDSC + c) * NTHR + tid] = u.v;
        }
    }

    float bias[4] = {0.f, 0.f, 0.f, 0.f};
    if (s == 0) {
        #pragma unroll
        for (int g = 0; g < 4; ++g)
            bias[g] = b_ih[j + g * 256] + b_hh[j + g * 256];
    }

    float cst = 0.f, hval = 0.f;
    if (s == 0) {
        cst  = c0[b * HID + j];
        hval = h0[b * HID + j];
        hbuf[j] = (_Float16)hval;
    }
    if (tid < 8) {
        hbuf[256 + tid]        = (_Float16)0.f;
        hbuf[HPAD + 256 + tid] = (_Float16)0.f;
    }

    for (int t = 0; t < T_STEPS; ++t) {
        __syncthreads();
        const f16x8* hb = (const f16x8*)(hbuf + (t & 1) * HPAD);

        float acc[4] = {0.f, 0.f, 0.f, 0.f};
        if (s != 0) {
            const float4* Wi4 = (const float4*)W_ih;
            const float4* xv4 = (const float4*)(x + ((size_t)t * BATCH + b) * IN)
                                + (s - 1) * 8;
            #pragma unroll
            for (int q = 0; q < 8; ++q) {
                float4 xv = xv4[q];
                #pragma unroll
                for (int g = 0; g < 4; ++g) {
                    float4 wv = Wi4[(j + 256 * g) * 16 + (s - 1) * 8 + q];
                    acc[g] += wv.x * xv.x + wv.y * xv.y + wv.z * xv.z + wv.w * xv.w;
                }
            }
        }
        #pragma unroll
        for (int c = 0; c < REGC; ++c) {
            union { f16x8 v; f16x2 p[4]; } hu;
            hu.v = hb[s * KC + c];
            #pragma unroll
            for (int uu = 0; uu < 4; ++uu) {
                #pragma unroll
                for (int g = 0; g < 4; ++g)
                    acc[g] = fdot2(wr[g * 32 + c * 4 + uu], hu.p[uu], acc[g]);
            }
        }
        #pragma unroll
        for (int c = 0; c < LDSC; ++c) {
            union { f16x8 v; f16x2 p[4]; } hu;
            hu.v = hb[s * KC + REGC + c];
            #pragma unroll
            for (int g = 0; g < 4; ++g) {
                union { f16x8 v; f16x2 p[4]; } wu;
                wu.v = wt8[(g * LDSC + c) * NTHR + tid];
                #pragma unroll
                for (int uu = 0; uu < 4; ++uu)
                    acc[g] = fdot2(wu.p[uu], hu.p[uu], acc[g]);
            }
        }
        if (s != 0)
            psum[(s - 1) * 256 + j] = float4{acc[0], acc[1], acc[2], acc[3]};
        __syncthreads();
        if (s == 0) {
            float4 p1 = psum[j];
            float4 p2 = psum[256 + j];
            float gi = sigf(acc[0] + p1.x + p2.x + bias[0]);
            float gf = sigf(acc[1] + p1.y + p2.y + bias[1]);
            float gg = tanh_fast(acc[2] + p1.z + p2.z + bias[2]);
            float go = sigf(acc[3] + p1.w + p2.w + bias[3]);
            cst  = gf * cst + gi * gg;
            hval = go * tanh_fast(cst);
            hbuf[((t + 1) & 1) * HPAD + j] = (_Float16)hval;
        }
    }

    if (s == 0) esh[j] = hval * W_lin[j];
    __syncthreads();
    if (tid == 0) {
        float z = b_lin[0];
        for (int n = 0; n < 256; ++n) z += esh[n];
        out[b] = sigf(z);
    }
}

extern "C" void kernel_launch(void* const* d_in, const int* in_sizes, int n_in,
                              void* d_out, int out_size, void* d_ws, size_t ws_size,
                              hipStream_t stream) {
    const float* x     = (const float*)d_in[0];
    const float* W_ih  = (const float*)d_in[1];
    const float* W_hh  = (const float*)d_in[2];
    const float* b_ih  = (const float*)d_in[3];
    const float* b_hh  = (const float*)d_in[4];
    const float* W_lin = (const float*)d_in[5];
    const float* b_lin = (const float*)d_in[6];
    const float* h0    = (const float*)d_in[7];
    const float* c0    = (const float*)d_in[8];
    float* out = (float*)d_out;

    const size_t need = (size_t)T_STEPS * BATCH * G4 * sizeof(_Float16); // 128 MB
    if (ws_size >= need) {
        _Float16* xg = (_Float16*)d_ws;
        xg_precompute<<<dim3(BATCH, 32), 256, 0, stream>>>(x, W_ih, b_ih, b_hh, xg);
        lstm_mfma<<<dim3(BATCH), 1024, 0, stream>>>(
            W_hh, W_lin, b_lin, h0, c0, xg, out);
    } else {
        (void)hipFuncSetAttribute((const void*)lstm_fb,
                                  hipFuncAttributeMaxDynamicSharedMemorySize,
                                  SMEM_BYTES);
        lstm_fb<<<dim3(BATCH), NTHR, SMEM_BYTES, stream>>>(
            x, W_ih, W_hh, b_ih, b_hh, W_lin, b_lin, h0, c0, out);
    }
}

// Round 4
// 2976.604 us; speedup vs baseline: 1.6294x; 1.6171x over previous
//
#include <hip/hip_runtime.h>
#include <hip/hip_bf16.h>

// LSTM T=4096, B=16, I=64, H=256 (4H=1024 gate rows), O=1.
//
// R19 = R13 RESTORED + exp2-folded epilogue.
// R16/R18 post-mortem: both hybrid pipe-splits landed at ~2715-2730 cyc/step
// regardless of DS load (1056 vs 2688 cyc) -> limiter was sdot4's SCALAR
// FALLBACK (~12-16 VALU ops each; gfx950 ISA lists no v_dot*). VALU int8-dot
// offload is dead on this target. Per-CU floor stands: 256 broadcast-
// redundant MFMAs/CU-step = 1306 cyc + ~440 cyc serial handoff.
// This round: verified R13 structure, epilogue trimmed:
//   - xg pre-scaled by log2e (2*log2e for tanh gate) in kernel A; log2e
//     folded into ksc -> sigmoid/tanh skip the range-reduction multiply
//     (exp2 directly, negation via input modifier).
//   - h-quantize: fma(go*127, tanh_c, MAGIC); per-step hval multiply
//     removed from the chain (computed only at t=T-1).
// MFMA/int math identical to R13 => absmax ~2e-3 expected.
//
// Structure (verified R10/R11/R13): 16 WGs x 1024 thr (16 waves, 4/SIMD).
// Wave w, lane col=l&15 owns unit u=w*16+col; gate rows g*256+u. Weights:
// 4x4 i32x4 = 64 VGPRs of MFMA operands (allocator-proof). Per-gate-row
// symmetric int8 quant, preact = (rowmax/127^2)*acc_int + xg, int32 exact.
// h int8 in LDS identity layout (4x b128 broadcast, 0 conflicts), double-
// buffered; magic-number RNE h-quantize; ONE barrier/step; all-lane
// redundant epilogue; xg fp16 [t][b][u*4+g] prefetched via pointer.

typedef _Float16 f16x2 __attribute__((ext_vector_type(2)));
typedef _Float16 f16x4 __attribute__((ext_vector_type(4)));
typedef int      i32x4 __attribute__((ext_vector_type(4)));

#define T_STEPS 4096
#define BATCH   16
#define IN      64
#define HID     256
#define G4      1024

#define LOG2E 1.44269504088896f

__device__ __forceinline__ float fdot2(f16x2 a, f16x2 b, float c) {
#if __has_builtin(__builtin_amdgcn_fdot2)
    return __builtin_amdgcn_fdot2(a, b, c, false);
#else
    return c + (float)a.x * (float)b.x + (float)a.y * (float)b.y;
#endif
}

__device__ __forceinline__ float fast_rcp(float x) {
#if __has_builtin(__builtin_amdgcn_rcpf)
    return __builtin_amdgcn_rcpf(x);
#else
    return 1.0f / x;
#endif
}

__device__ __forceinline__ float exp2_fast(float x) {
#if __has_builtin(__builtin_amdgcn_exp2f)
    return __builtin_amdgcn_exp2f(x);
#else
    return exp2f(x);
#endif
}

// sig2(x2) = sigmoid(x) where x2 = x*log2e  (one exp2, neg via modifier)
__device__ __forceinline__ float sig2(float x2) {
    return fast_rcp(1.0f + exp2_fast(-x2));
}
// th2(x2) = tanh(x) where x2 = x*2*log2e
__device__ __forceinline__ float th2(float x2) {
    return __builtin_fmaf(2.0f, fast_rcp(1.0f + exp2_fast(-x2)), -1.0f);
}

// unscaled helpers (fallback kernel only)
__device__ __forceinline__ float sigf(float x) {
    return fast_rcp(1.0f + __expf(-x));
}
__device__ __forceinline__ float tanh_fast(float x) {
    return 2.0f * sigf(2.0f * x) - 1.0f;
}

// ---------------- Kernel A: x_gates precompute (transposed, log2e-scaled) --
__global__ __launch_bounds__(256) void xg_precompute(
    const float* __restrict__ x, const float* __restrict__ W_ih,
    const float* __restrict__ b_ih, const float* __restrict__ b_hh,
    _Float16* __restrict__ xg)
{
    const int b   = blockIdx.x;
    const int t0  = blockIdx.y * 128;
    const int tid = threadIdx.x;

    __shared__ __align__(16) f16x2 xs2[IN / 2];

    f16x2 wih[4][32];
    float bias[4];
    const float2* W2 = (const float2*)W_ih;
    #pragma unroll
    for (int g = 0; g < 4; ++g) {
        const int r = tid + g * 256;
        #pragma unroll
        for (int m = 0; m < 32; ++m) {
            float2 v = W2[r * 32 + m];
            wih[g][m] = f16x2{(_Float16)v.x, (_Float16)v.y};
        }
        bias[g] = b_ih[r] + b_hh[r];
    }

    // per-gate epilogue pre-scale: sig gates * log2e, tanh gate * 2log2e
    const float esc[4] = {LOG2E, LOG2E, 2.0f * LOG2E, LOG2E};

    for (int tt = 0; tt < 128; ++tt) {
        const int t = t0 + tt;
        if (tid < 32) {
            float2 v = ((const float2*)x)[(t * BATCH + b) * 32 + tid];
            xs2[tid] = f16x2{(_Float16)v.x, (_Float16)v.y};
        }
        __syncthreads();
        float acc[4] = {bias[0], bias[1], bias[2], bias[3]};
        #pragma unroll
        for (int m = 0; m < 32; ++m) {
            f16x2 xv = xs2[m];
            #pragma unroll
            for (int g = 0; g < 4; ++g) acc[g] = fdot2(wih[g][m], xv, acc[g]);
        }
        f16x4 v4 = f16x4{(_Float16)(acc[0] * esc[0]), (_Float16)(acc[1] * esc[1]),
                         (_Float16)(acc[2] * esc[2]), (_Float16)(acc[3] * esc[3])};
        ((f16x4*)xg)[(t * BATCH + b) * 256 + tid] = v4;
        __syncthreads();
    }
}

// ---------------- Kernel B: i8-MFMA persistent recurrence ----------------
__global__ __launch_bounds__(1024, 4) void lstm_mfma(
    const float* __restrict__ W_hh,  const float* __restrict__ W_lin,
    const float* __restrict__ b_lin, const float* __restrict__ h0,
    const float* __restrict__ c0,    const _Float16* __restrict__ xg,
    float* __restrict__ out)
{
    const int b   = blockIdx.x;
    const int tid = threadIdx.x;
    const int w   = tid >> 6;     // wave 0..15
    const int l   = tid & 63;     // lane
    const int col = l & 15;       // MFMA col for this lane
    const int g4  = l >> 4;       // k lane-group 0..3

    __shared__ __align__(16) signed char hs[2][256];  // h int8, identity layout
    __shared__ float esh[256];

    const int u = w * 16 + col;   // unit this lane covers

    // ---- one-time: per-gate-row max, then W_hh -> int8 B-fragments ----
    const float4* Wh4 = (const float4*)W_hh;          // row stride 64 float4
    float qs[4], ksc[4];
    {
        float rm[4];
        #pragma unroll
        for (int g = 0; g < 4; ++g) {
            const int row = g * 256 + u;
            float m = 0.0f;
            #pragma unroll
            for (int c = 0; c < 4; ++c) {
                #pragma unroll
                for (int d = 0; d < 4; ++d) {
                    float4 v = Wh4[row * 64 + 16 * c + 4 * g4 + d];
                    m = fmaxf(m, fmaxf(fmaxf(fabsf(v.x), fabsf(v.y)),
                                       fmaxf(fabsf(v.z), fabsf(v.w))));
                }
            }
            rm[g] = m;
        }
        const float esc[4] = {LOG2E, LOG2E, 2.0f * LOG2E, LOG2E};
        #pragma unroll
        for (int g = 0; g < 4; ++g) {                  // max across g4 groups
            rm[g] = fmaxf(rm[g], __shfl_xor(rm[g], 16, 64));
            rm[g] = fmaxf(rm[g], __shfl_xor(rm[g], 32, 64));
            rm[g] = fmaxf(rm[g], 1e-20f);
            qs[g]  = 127.0f / rm[g];
            ksc[g] = rm[g] * (1.0f / 16129.0f) * esc[g];   // rm/127^2 * exp2 scale
        }
    }
    i32x4 wf[4][4];
    #pragma unroll
    for (int g = 0; g < 4; ++g) {
        const int row = g * 256 + u;
        #pragma unroll
        for (int c = 0; c < 4; ++c) {
            union { int i[4]; i32x4 v; } uu;
            #pragma unroll
            for (int d = 0; d < 4; ++d) {
                float4 v = Wh4[row * 64 + 16 * c + 4 * g4 + d];
                int b0 = (int)rintf(v.x * qs[g]) & 255;
                int b1 = (int)rintf(v.y * qs[g]) & 255;
                int b2 = (int)rintf(v.z * qs[g]) & 255;
                int b3 = (int)rintf(v.w * qs[g]) & 255;
                uu.i[d] = b0 | (b1 << 8) | (b2 << 16) | (b3 << 24);
            }
            wf[g][c] = uu.v;
        }
    }

    // ---- state (lane l<16 owns unit u's write) ----
    const float MAGIC = 12582912.0f;                   // 1.5 * 2^23
    float cst  = c0[b * HID + u];
    float hval = h0[b * HID + u];
    if (l < 16) {
        union { float f; int i; } m0;
        m0.f = __builtin_fmaf(hval, 127.0f, MAGIC);    // RNE int in low bits
        hs[0][u] = (signed char)(m0.i & 0xff);
    }

    union XU { uint2 i; f16x4 h; };
    const uint2* xp = (const uint2*)xg + b * 256 + u;  // stride BATCH*256/step
    XU xc; xc.i = *xp;
    xp += BATCH * 256;

    const float N2L = -2.0f * LOG2E;                   // for tanh(cst)

    for (int t = 0; t < T_STEPS; ++t) {
        __syncthreads();   // h(t) in hs[t&1] visible

        // A fragments: chunk c = bytes [64c + 16*g4, +16) -> 4x b128 broadcast
        const uint4* hsv = (const uint4*)(&hs[t & 1][0]);
        union AU { uint4 q; i32x4 v; } a0, a1, a2, a3;
        a0.q = hsv[g4];
        a1.q = hsv[4 + g4];
        a2.q = hsv[8 + g4];
        a3.q = hsv[12 + g4];

        // prefetch next step's x-gates (pointer-incremented)
        XU xn;
        if (t + 1 < T_STEPS) { xn.i = *xp; xp += BATCH * 256; }
        else                 { xn = xc; }

        i32x4 acc0 = {0, 0, 0, 0};
        i32x4 acc1 = {0, 0, 0, 0};
        i32x4 acc2 = {0, 0, 0, 0};
        i32x4 acc3 = {0, 0, 0, 0};

        acc0 = __builtin_amdgcn_mfma_i32_16x16x64_i8(a0.v, wf[0][0], acc0, 0, 0, 0);
        acc1 = __builtin_amdgcn_mfma_i32_16x16x64_i8(a0.v, wf[1][0], acc1, 0, 0, 0);
        acc2 = __builtin_amdgcn_mfma_i32_16x16x64_i8(a0.v, wf[2][0], acc2, 0, 0, 0);
        acc3 = __builtin_amdgcn_mfma_i32_16x16x64_i8(a0.v, wf[3][0], acc3, 0, 0, 0);
        acc0 = __builtin_amdgcn_mfma_i32_16x16x64_i8(a1.v, wf[0][1], acc0, 0, 0, 0);
        acc1 = __builtin_amdgcn_mfma_i32_16x16x64_i8(a1.v, wf[1][1], acc1, 0, 0, 0);
        acc2 = __builtin_amdgcn_mfma_i32_16x16x64_i8(a1.v, wf[2][1], acc2, 0, 0, 0);
        acc3 = __builtin_amdgcn_mfma_i32_16x16x64_i8(a1.v, wf[3][1], acc3, 0, 0, 0);
        acc0 = __builtin_amdgcn_mfma_i32_16x16x64_i8(a2.v, wf[0][2], acc0, 0, 0, 0);
        acc1 = __builtin_amdgcn_mfma_i32_16x16x64_i8(a2.v, wf[1][2], acc1, 0, 0, 0);
        acc2 = __builtin_amdgcn_mfma_i32_16x16x64_i8(a2.v, wf[2][2], acc2, 0, 0, 0);
        acc3 = __builtin_amdgcn_mfma_i32_16x16x64_i8(a2.v, wf[3][2], acc3, 0, 0, 0);
        acc0 = __builtin_amdgcn_mfma_i32_16x16x64_i8(a3.v, wf[0][3], acc0, 0, 0, 0);
        acc1 = __builtin_amdgcn_mfma_i32_16x16x64_i8(a3.v, wf[1][3], acc1, 0, 0, 0);
        acc2 = __builtin_amdgcn_mfma_i32_16x16x64_i8(a3.v, wf[2][3], acc2, 0, 0, 0);
        acc3 = __builtin_amdgcn_mfma_i32_16x16x64_i8(a3.v, wf[3][3], acc3, 0, 0, 0);

        // D rows identical -> acc reg0 of ANY lane = int preact(col).
        // All-lane redundant epilogue; preacts are already exp2-scaled.
        float p0 = __builtin_fmaf((float)acc0[0], ksc[0], (float)xc.h[0]);
        float p1 = __builtin_fmaf((float)acc1[0], ksc[1], (float)xc.h[1]);
        float p2 = __builtin_fmaf((float)acc2[0], ksc[2], (float)xc.h[2]);
        float p3 = __builtin_fmaf((float)acc3[0], ksc[3], (float)xc.h[3]);
        float gi = sig2(p0);
        float gf = sig2(p1);
        float gg = th2(p2);
        float go = sig2(p3);
        cst = __builtin_fmaf(gf, cst, gi * gg);
        float thc   = th2(cst * (-N2L));               // tanh(cst)
        float go127 = go * 127.0f;                     // off-chain
        if (l < 16) {
            union { float f; int i; } mg;
            mg.f = __builtin_fmaf(go127, thc, MAGIC);  // RNE, low byte = i8
            hs[(t + 1) & 1][u] = (signed char)(mg.i & 0xff);
        }
        if (t == T_STEPS - 1) hval = go * thc;         // full-precision h_T
        xc = xn;
    }

    // ---- epilogue: y[b] = sigmoid(h . W_lin + b_lin) ----
    if (l < 16) esh[u] = hval * W_lin[u];
    __syncthreads();
    if (tid == 0) {
        float z = b_lin[0];
        for (int n = 0; n < 256; ++n) z += esh[n];
        out[b] = sigf(z);
    }
}

// ---------------- Fallback (ws too small): R6 dot2 kernel, x streamed ------
#define NTHR 768
#define KC   11
#define REGC 8
#define LDSC 3
#define HPAD 264
#define WT_OFF   0
#define HB_OFF   147456
#define PS_OFF   148512
#define ESH_OFF  156704
#define SMEM_BYTES 157728
typedef _Float16 f16x8 __attribute__((ext_vector_type(8)));

__global__ __launch_bounds__(NTHR, 3) void lstm_fb(
    const float* __restrict__ x,     const float* __restrict__ W_ih,
    const float* __restrict__ W_hh,  const float* __restrict__ b_ih,
    const float* __restrict__ b_hh,  const float* __restrict__ W_lin,
    const float* __restrict__ b_lin, const float* __restrict__ h0,
    const float* __restrict__ c0,    float* __restrict__ out)
{
    const int b   = blockIdx.x;
    const int tid = threadIdx.x;
    const int j   = tid & 255;
    const int s   = tid >> 8;

    extern __shared__ __align__(16) char smem[];
    f16x8*    wt8  = (f16x8*)(smem + WT_OFF);
    _Float16* hbuf = (_Float16*)(smem + HB_OFF);
    float4*   psum = (float4*)(smem + PS_OFF);
    float*    esh  = (float*)(smem + ESH_OFF);

    f16x2 wr[128];
    const float4* Wh4 = (const float4*)W_hh;
    #pragma unroll
    for (int g = 0; g < 4; ++g) {
        const int r = j + 256 * g;
        #pragma unroll
        for (int c = 0; c < REGC; ++c) {
            const int f4i = r * 64 + (88 * s + 8 * c) / 4;
            float4 a = Wh4[f4i];
            float4 d = Wh4[f4i + 1];
            wr[g * 32 + c * 4 + 0] = f16x2{(_Float16)a.x, (_Float16)a.y};
            wr[g * 32 + c * 4 + 1] = f16x2{(_Float16)a.z, (_Float16)a.w};
            wr[g * 32 + c * 4 + 2] = f16x2{(_Float16)d.x, (_Float16)d.y};
            wr[g * 32 + c * 4 + 3] = f16x2{(_Float16)d.z, (_Float16)d.w};
        }
        #pragma unroll
        for (int c = 0; c < LDSC; ++c) {
            const int k0 = 88 * s + 8 * (REGC + c);
            union { f16x8 v; f16x2 p[4]; } u;
            if (k0 < 256) {
                float4 a = Wh4[r * 64 + k0 / 4];
                float4 d = Wh4[r * 64 + k0 / 4 + 1];
                u.p[0] = f16x2{(_Float16)a.x, (_Float16)a.y};
                u.p[1] = f16x2{(_Float16)a.z, (_Float16)a.w};
                u.p[2] = f16x2{(_Float16)d.x, (_Float16)d.y};
                u.p[3] = f16x2{(_Float16)d.z, (_Float16)d.w};
            } else {
                u.p[0] = f16x2{0, 0}; u.p[1] = f16x2{0, 0};
                u.p[2] = f16x2{0, 0}; u.p[3] = f16x2{0, 0};
            }
            wt8[(g * LDSC + c) * NTHR + tid] = u.v;
        }
    }

    float bias[4] = {0.f, 0.f, 0.f, 0.f};
    if (s == 0) {
        #pragma unroll
        for (int g = 0; g < 4; ++g)
            bias[g] = b_ih[j + g * 256] + b_hh[j + g * 256];
    }

    float cst = 0.f, hval = 0.f;
    if (s == 0) {
        cst  = c0[b * HID + j];
        hval = h0[b * HID + j];
        hbuf[j] = (_Float16)hval;
    }
    if (tid < 8) {
        hbuf[256 + tid]        = (_Float16)0.f;
        hbuf[HPAD + 256 + tid] = (_Float16)0.f;
    }

    for (int t = 0; t < T_STEPS; ++t) {
        __syncthreads();
        const f16x8* hb = (const f16x8*)(hbuf + (t & 1) * HPAD);

        float acc[4] = {0.f, 0.f, 0.f, 0.f};
        if (s != 0) {
            const float4* Wi4 = (const float4*)W_ih;
            const float4* xv4 = (const float4*)(x + ((size_t)t * BATCH + b) * IN)
                                + (s - 1) * 8;
            #pragma unroll
            for (int q = 0; q < 8; ++q) {
                float4 xv = xv4[q];
                #pragma unroll
                for (int g = 0; g < 4; ++g) {
                    float4 wv = Wi4[(j + 256 * g) * 16 + (s - 1) * 8 + q];
                    acc[g] += wv.x * xv.x + wv.y * xv.y + wv.z * xv.z + wv.w * xv.w;
                }
            }
        }
        #pragma unroll
        for (int c = 0; c < REGC; ++c) {
            union { f16x8 v; f16x2 p[4]; } hu;
            hu.v = hb[s * KC + c];
            #pragma unroll
            for (int uu = 0; uu < 4; ++uu) {
                #pragma unroll
                for (int g = 0; g < 4; ++g)
                    acc[g] = fdot2(wr[g * 32 + c * 4 + uu], hu.p[uu], acc[g]);
            }
        }
        #pragma unroll
        for (int c = 0; c < LDSC; ++c) {
            union { f16x8 v; f16x2 p[4]; } hu;
            hu.v = hb[s * KC + REGC + c];
            #pragma unroll
            for (int g = 0; g < 4; ++g) {
                union { f16x8 v; f16x2 p[4]; } wu;
                wu.v = wt8[(g * LDSC + c) * NTHR + tid];
                #pragma unroll
                for (int uu = 0; uu < 4; ++uu)
                    acc[g] = fdot2(wu.p[uu], hu.p[uu], acc[g]);
            }
        }
        if (s != 0)
            psum[(s - 1) * 256 + j] = float4{acc[0], acc[1], acc[2], acc[3]};
        __syncthreads();
        if (s == 0) {
            float4 p1 = psum[j];
            float4 p2 = psum[256 + j];
            float gi = sigf(acc[0] + p1.x + p2.x + bias[0]);
            float gf = sigf(acc[1] + p1.y + p2.y + bias[1]);
            float gg = tanh_fast(acc[2] + p1.z + p2.z + bias[2]);
            float go = sigf(acc[3] + p1.w + p2.w + bias[3]);
            cst  = gf * cst + gi * gg;
            hval = go * tanh_fast(cst);
            hbuf[((t + 1) & 1) * HPAD + j] = (_Float16)hval;
        }
    }

    if (s == 0) esh[j] = hval * W_lin[j];
    __syncthreads();
    if (tid == 0) {
        float z = b_lin[0];
        for (int n = 0; n < 256; ++n) z += esh[n];
        out[b] = sigf(z);
    }
}

extern "C" void kernel_launch(void* const* d_in, const int* in_sizes, int n_in,
                              void* d_out, int out_size, void* d_ws, size_t ws_size,
                              hipStream_t stream) {
    const float* x     = (const float*)d_in[0];
    const float* W_ih  = (const float*)d_in[1];
    const float* W_hh  = (const float*)d_in[2];
    const float* b_ih  = (const float*)d_in[3];
    const float* b_hh  = (const float*)d_in[4];
    const float* W_lin = (const float*)d_in[5];
    const float* b_lin = (const float*)d_in[6];
    const float* h0    = (const float*)d_in[7];
    const float* c0    = (const float*)d_in[8];
    float* out = (float*)d_out;

    const size_t need = (size_t)T_STEPS * BATCH * G4 * sizeof(_Float16); // 128 MB
    if (ws_size >= need) {
        _Float16* xg = (_Float16*)d_ws;
        xg_precompute<<<dim3(BATCH, 32), 256, 0, stream>>>(x, W_ih, b_ih, b_hh, xg);
        lstm_mfma<<<dim3(BATCH), 1024, 0, stream>>>(
            W_hh, W_lin, b_lin, h0, c0, xg, out);
    } else {
        (void)hipFuncSetAttribute((const void*)lstm_fb,
                                  hipFuncAttributeMaxDynamicSharedMemorySize,
                                  SMEM_BYTES);
        lstm_fb<<<dim3(BATCH), NTHR, SMEM_BYTES, stream>>>(
            x, W_ih, W_hh, b_ih, b_hh, W_lin, b_lin, h0, c0, out);
    }
}